// Round 4
// baseline (567.581 us; speedup 1.0000x reference)
//
#include <hip/hip_runtime.h>
#include <hip/hip_bf16.h>

// GPTNeoXAttention + CAM mask pipeline, MI355X (gfx950)
// B=4 S=1024 HID=2048 NH=16 HD=128 ROT=32, sb=rb=103
//
// R4: GEMM cores rebuilt as 128x384 (qkv) / 128x256 (out) with B-resident
// fragments (20 ds_read per 48 MFMA), 2 phases/K-tile, counted vmcnt,
// exact-round grids (512 / 256 blocks), XCD-patch swizzle.

#define S_LEN 1024
#define NHEAD 16
#define HDIM  128
#define HID   2048
#define SB    103
#define RB    103
#define TMIN  206
#define NT    818
#define NKT   32          // K=2048 / BK=64

typedef __bf16 bf16x8 __attribute__((ext_vector_type(8)));
typedef __bf16 bf16x4 __attribute__((ext_vector_type(4)));
typedef float  f32x4  __attribute__((ext_vector_type(4)));

#define PLDS_STRIDE 648

// ---------------- threefry2x32 (JAX-compatible) ----------------
__device__ __forceinline__ void tf2x32(unsigned k0, unsigned k1,
                                       unsigned x0, unsigned x1,
                                       unsigned& o0, unsigned& o1) {
  unsigned ks2 = k0 ^ k1 ^ 0x1BD11BDAu;
  x0 += k0; x1 += k1;
#define TFR(r) { x0 += x1; x1 = (x1 << r) | (x1 >> (32 - r)); x1 ^= x0; }
  TFR(13) TFR(15) TFR(26) TFR(6)   x0 += k1;  x1 += ks2 + 1u;
  TFR(17) TFR(29) TFR(16) TFR(24)  x0 += ks2; x1 += k0 + 2u;
  TFR(13) TFR(15) TFR(26) TFR(6)   x0 += k0;  x1 += k1 + 3u;
  TFR(17) TFR(29) TFR(16) TFR(24)  x0 += k1;  x1 += ks2 + 4u;
  TFR(13) TFR(15) TFR(26) TFR(6)   x0 += ks2; x1 += k0 + 5u;
#undef TFR
  o0 = x0; o1 = x1;
}
__device__ __forceinline__ float tfu(unsigned b) {
  return __builtin_bit_cast(float, (b >> 9) | 0x3f800000u) - 1.0f;
}

// ---------------- casts / transposes ----------------
__global__ __launch_bounds__(256) void k_cast_bf16(const float* __restrict__ in,
                                                   __hip_bfloat16* __restrict__ out, int n4) {
  int i = blockIdx.x * 256 + threadIdx.x;
  if (i >= n4) return;
  float4 v = ((const float4*)in)[i];
  __hip_bfloat162 lo = __float22bfloat162_rn(make_float2(v.x, v.y));
  __hip_bfloat162 hi = __float22bfloat162_rn(make_float2(v.z, v.w));
  ((__hip_bfloat162*)out)[2*i]   = lo;
  ((__hip_bfloat162*)out)[2*i+1] = hi;
}

// W[K][N] f32 -> Wt[N][K] bf16
__global__ __launch_bounds__(256) void k_transpose_cast(const float* __restrict__ W,
                                                        __hip_bfloat16* __restrict__ Wt,
                                                        int K, int N) {
  __shared__ float tile[32][33];
  int n0 = blockIdx.x * 32, k0 = blockIdx.y * 32;
  int tx = threadIdx.x, ty = threadIdx.y;
  #pragma unroll
  for (int i = 0; i < 32; i += 8)
    tile[ty + i][tx] = W[(size_t)(k0 + ty + i) * N + n0 + tx];
  __syncthreads();
  #pragma unroll
  for (int i = 0; i < 32; i += 8)
    Wt[(size_t)(n0 + ty + i) * K + k0 + tx] = __float2bfloat16(tile[tx][ty + i]);
}

// Vf [bh][k][d] f32 -> Vt [bh][d][k] bf16
__global__ __launch_bounds__(256) void k_vtrans(const float* __restrict__ Vf,
                                                __hip_bfloat16* __restrict__ Vt) {
  __shared__ float tile[32][33];
  int k0 = blockIdx.x * 32, d0 = blockIdx.y * 32, bh = blockIdx.z;
  int tx = threadIdx.x, ty = threadIdx.y;
  #pragma unroll
  for (int i = 0; i < 32; i += 8)
    tile[ty + i][tx] = Vf[((size_t)bh * S_LEN + (k0 + ty + i)) * HDIM + d0 + tx];
  __syncthreads();
  #pragma unroll
  for (int i = 0; i < 32; i += 8)
    Vt[((size_t)bh * HDIM + (d0 + ty + i)) * S_LEN + k0 + tx] = __float2bfloat16(tile[tx][ty + i]);
}

// ================= 128xN_TILE BK=64 8-wave GEMM core =================
// A: Mx2048 bf16 rowmajor, B: Nx2048 bf16 rowmajor. LDS layout per tile row:
// byte(r, chunk c) = r*128 + ((c ^ (r&7))<<4), c in [0,8) (16B chunks, K=64).
// Staged linearly via inverse-swizzled global source (rule #21).
// 8 waves = 2M x 4N; per-wave 64 rows x (NF*16) cols; B-frags register-resident.
// Phases per K-tile: ph0 {read B(2*NF)+A01(4) | bar | lgkm | 24 MFMA | bar}
//                    ph1 {read A23(4) + stage kt+2 | bar | lgkm | MFMA | bar}
//                    boundary {stage rest; vmcnt(2+BI); bar}

template<int N> __device__ __forceinline__ void waitvm() {
  if constexpr (N == 8)      asm volatile("s_waitcnt vmcnt(8)" ::: "memory");
  else if constexpr (N == 6) asm volatile("s_waitcnt vmcnt(6)" ::: "memory");
  else                       asm volatile("s_waitcnt vmcnt(0)" ::: "memory");
}

template<int NF, int BROWS, int BI>
struct GemmCore {
  static constexpr int LDS_BYTES = 32768 + 2 * BROWS * 128;

  const char* A; const char* B;
  char* lds;
  long rowA0, rowB0;
  int lane, w, wm, wn, l15, g;

  __device__ __forceinline__ void stA(char* dst, int kt) {
    int rl = lane >> 3, cs = lane & 7;
    #pragma unroll
    for (int j = 0; j < 2; j++) {
      int r = w * 16 + j * 8 + rl;
      int c = cs ^ (r & 7);
      const char* src = A + (size_t)(rowA0 + r) * 4096 + (size_t)kt * 128 + (c << 4);
      __builtin_amdgcn_global_load_lds((const __attribute__((address_space(1))) void*)src,
          (__attribute__((address_space(3))) void*)(dst + (w * 16 + j * 8) * 128), 16, 0, 0);
    }
  }
  __device__ __forceinline__ void stB(char* dst, int kt) {
    int rl = lane >> 3, cs = lane & 7;
    #pragma unroll
    for (int j = 0; j < BI; j++) {
      int r = w * (BROWS / 8) + j * 8 + rl;
      int c = cs ^ (r & 7);
      const char* src = B + (size_t)(rowB0 + r) * 4096 + (size_t)kt * 128 + (c << 4);
      __builtin_amdgcn_global_load_lds((const __attribute__((address_space(1))) void*)src,
          (__attribute__((address_space(3))) void*)(dst + (w * (BROWS / 8) + j * 8) * 128), 16, 0, 0);
    }
  }
  __device__ __forceinline__ bf16x8 rdA(const char* buf, int mi, int kk) {
    int r = wm * 64 + mi * 16 + l15;
    return *(const bf16x8*)(buf + r * 128 + (((kk * 4 + g) ^ (r & 7)) << 4));
  }
  __device__ __forceinline__ bf16x8 rdB(const char* buf, int nf, int kk) {
    int r = wn * (NF * 16) + nf * 16 + l15;
    return *(const bf16x8*)(buf + r * 128 + (((kk * 4 + g) ^ (r & 7)) << 4));
  }

  __device__ __forceinline__ void run(f32x4 (&acc)[4][NF]) {
    const int tid = threadIdx.x;
    lane = tid & 63; w = tid >> 6;
    wm = w >> 2; wn = w & 3;
    l15 = lane & 15; g = lane >> 4;
    char* Ab[2] = { lds, lds + 16384 };
    char* Bb[2] = { lds + 32768, lds + 32768 + BROWS * 128 };
    // prologue: stage kt0, kt1
    stA(Ab[0], 0); stB(Bb[0], 0);
    stA(Ab[1], 1); stB(Bb[1], 1);
    waitvm<2 + BI>();
    __builtin_amdgcn_s_barrier();
    #pragma unroll 1
    for (int kt = 0; kt < NKT; kt++) {
      const int s = kt & 1;
      const bool st = (kt + 2) < NKT;
      bf16x8 b[NF][2], a0[2][2];
      // ---- ph0: read all B + A-half0
      #pragma unroll
      for (int nf = 0; nf < NF; nf++) {
        b[nf][0] = rdB(Bb[s], nf, 0);
        b[nf][1] = rdB(Bb[s], nf, 1);
      }
      #pragma unroll
      for (int mi = 0; mi < 2; mi++) {
        a0[mi][0] = rdA(Ab[s], mi, 0);
        a0[mi][1] = rdA(Ab[s], mi, 1);
      }
      __builtin_amdgcn_s_barrier();
      asm volatile("s_waitcnt lgkmcnt(0)" ::: "memory");
      __builtin_amdgcn_sched_barrier(0);
      __builtin_amdgcn_s_setprio(1);
      #pragma unroll
      for (int kk = 0; kk < 2; kk++)
        #pragma unroll
        for (int mi = 0; mi < 2; mi++)
          #pragma unroll
          for (int nf = 0; nf < NF; nf++)
            acc[mi][nf] = __builtin_amdgcn_mfma_f32_16x16x32_bf16(
                a0[mi][kk], b[nf][kk], acc[mi][nf], 0, 0, 0);
      __builtin_amdgcn_s_setprio(0);
      __builtin_amdgcn_s_barrier();
      // ---- ph1: read A-half1; stage kt+2 (B all; A by waves 0,1,4,5)
      bf16x8 a1[2][2];
      #pragma unroll
      for (int mi = 0; mi < 2; mi++) {
        a1[mi][0] = rdA(Ab[s], 2 + mi, 0);
        a1[mi][1] = rdA(Ab[s], 2 + mi, 1);
      }
      if (st) {
        stB(Bb[s], kt + 2);
        if (((w >> 1) & 1) == 0) stA(Ab[s], kt + 2);
      }
      __builtin_amdgcn_s_barrier();
      asm volatile("s_waitcnt lgkmcnt(0)" ::: "memory");
      __builtin_amdgcn_sched_barrier(0);
      __builtin_amdgcn_s_setprio(1);
      #pragma unroll
      for (int kk = 0; kk < 2; kk++)
        #pragma unroll
        for (int mi = 0; mi < 2; mi++)
          #pragma unroll
          for (int nf = 0; nf < NF; nf++)
            acc[2 + mi][nf] = __builtin_amdgcn_mfma_f32_16x16x32_bf16(
                a1[mi][kk], b[nf][kk], acc[2 + mi][nf], 0, 0, 0);
      __builtin_amdgcn_s_setprio(0);
      __builtin_amdgcn_s_barrier();
      // ---- boundary: finish A staging; counted vmcnt
      if (st) {
        if (((w >> 1) & 1) == 1) stA(Ab[s], kt + 2);
        waitvm<2 + BI>();
      } else {
        waitvm<0>();
      }
      __builtin_amdgcn_s_barrier();
    }
  }
};

// ---------------- GEMM qkv: 128x384 tile (tile = one head's Q|K|V) ----------------
__global__ __launch_bounds__(512, 2) void k_gemm_qkv3(const __hip_bfloat16* __restrict__ Xb,
    const __hip_bfloat16* __restrict__ WqkvT, const float* __restrict__ bqkv,
    const int* __restrict__ pid,
    __hip_bfloat16* __restrict__ Qb, __hip_bfloat16* __restrict__ Kb, float* __restrict__ Vf) {
  __shared__ __align__(16) char lds[32768 + 2 * 384 * 128];   // 128 KiB
  f32x4 acc[4][6];
  #pragma unroll
  for (int m = 0; m < 4; m++)
    #pragma unroll
    for (int n = 0; n < 6; n++)
      #pragma unroll
      for (int r = 0; r < 4; r++) acc[m][n][r] = 0.f;
  // XCD patch swizzle: 512 blocks, XCD x gets 8bm x 8bn patch
  int flat = blockIdx.y * 32 + blockIdx.x;
  int xcd = flat & 7, i = flat >> 3;
  int bm = (xcd & 3) * 8 + (i & 7);
  int bn = (xcd >> 2) * 8 + (i >> 3);
  GemmCore<6, 384, 6> core;
  core.A = (const char*)Xb; core.B = (const char*)WqkvT; core.lds = lds;
  core.rowA0 = (long)bm * 128; core.rowB0 = (long)bn * 384;
  core.run(acc);

  const int tid = threadIdx.x, lane = tid & 63, w = tid >> 6;
  const int wm = w >> 2, wn = w & 3;
  const int l15 = lane & 15, g = lane >> 4;
  const int h = bn;
  const int rowbase = bm * 128 + wm * 64 + g * 4;
  // bias
  #pragma unroll
  for (int nf = 0; nf < 6; nf++) {
    float bias = bqkv[h * 384 + wn * 96 + nf * 16 + l15];
    #pragma unroll
    for (int mi = 0; mi < 4; mi++)
      #pragma unroll
      for (int r = 0; r < 4; r++) acc[mi][nf][r] += bias;
  }
  // RoPE: wn==0 -> Q rot (nf pair 0,1); wn==1 -> K rot (nf pair 2,3); i = l15
  if (wn <= 1) {
    const int p0 = (wn == 0) ? 0 : 2, p1 = p0 + 1;
    const float invf = exp2f(-(float)l15 * 0.8304820237218406f); // 10000^(-i/16)
    #pragma unroll
    for (int mi = 0; mi < 4; mi++) {
      #pragma unroll
      for (int r = 0; r < 4; r++) {
        int row = rowbase + mi * 16 + r;
        int bb = row >> 10, s = row & 1023;
        float th = (float)pid[bb * S_LEN + s] * invf;
        float sn, cs;
        sincosf(th, &sn, &cs);
        float x1 = acc[mi][p0][r], x2 = acc[mi][p1][r];
        acc[mi][p0][r] = x1 * cs - x2 * sn;
        acc[mi][p1][r] = x2 * cs + x1 * sn;
      }
    }
  }
  // scatter (tile == head h)
  #pragma unroll
  for (int mi = 0; mi < 4; mi++) {
    #pragma unroll
    for (int nf = 0; nf < 6; nf++) {
      int j = wn * 96 + nf * 16 + l15;
      #pragma unroll
      for (int r = 0; r < 4; r++) {
        int row = rowbase + mi * 16 + r;
        int bb = row >> 10, s = row & 1023;
        size_t base = ((size_t)(bb * NHEAD + h) * S_LEN + s) * HDIM;
        float v = acc[mi][nf][r];
        if (j < 128)      Qb[base + j]       = __float2bfloat16(v);
        else if (j < 256) Kb[base + j - 128] = __float2bfloat16(v);
        else              Vf[base + j - 256] = v;
      }
    }
  }
}

// ---------------- GEMM out-proj: 128x256 tile ----------------
__global__ __launch_bounds__(512, 2) void k_gemm_out3(const __hip_bfloat16* __restrict__ Ab,
    const __hip_bfloat16* __restrict__ WdT, const float* __restrict__ bd,
    float* __restrict__ Out) {
  __shared__ __align__(16) char lds[32768 + 2 * 256 * 128];   // 96 KiB
  f32x4 acc[4][4];
  #pragma unroll
  for (int m = 0; m < 4; m++)
    #pragma unroll
    for (int n = 0; n < 4; n++)
      #pragma unroll
      for (int r = 0; r < 4; r++) acc[m][n][r] = 0.f;
  // XCD patch swizzle: 256 blocks, XCD x gets 8bm x 4bn patch
  int flat = blockIdx.y * 32 + blockIdx.x;
  int xcd = flat & 7, i = flat >> 3;
  int bm = (xcd & 3) * 8 + (i & 7);
  int bn = (xcd >> 2) * 4 + (i >> 3);
  GemmCore<4, 256, 4> core;
  core.A = (const char*)Ab; core.B = (const char*)WdT; core.lds = lds;
  core.rowA0 = (long)bm * 128; core.rowB0 = (long)bn * 256;
  core.run(acc);

  const int tid = threadIdx.x, lane = tid & 63, w = tid >> 6;
  const int wm = w >> 2, wn = w & 3;
  const int l15 = lane & 15, g = lane >> 4;
  const int rowbase = bm * 128 + wm * 64 + g * 4;
  #pragma unroll
  for (int nf = 0; nf < 4; nf++) {
    int col = bn * 256 + wn * 64 + nf * 16 + l15;
    float bias = bd[col];
    #pragma unroll
    for (int mi = 0; mi < 4; mi++)
      #pragma unroll
      for (int r = 0; r < 4; r++) {
        int row = rowbase + mi * 16 + r;
        Out[(size_t)row * HID + col] = acc[mi][nf][r] + bias;
      }
  }
}

// ---------------- banded flash attention ----------------
__device__ __forceinline__ bf16x8 lds_load8(const char* p) {
  bf16x4 lo = *(const bf16x4*)p;
  bf16x4 hi = *(const bf16x4*)(p + 8);
  bf16x8 v;
  v[0]=lo[0]; v[1]=lo[1]; v[2]=lo[2]; v[3]=lo[3];
  v[4]=hi[0]; v[5]=hi[1]; v[6]=hi[2]; v[7]=hi[3];
  return v;
}

template<int PHASE>
__global__ __launch_bounds__(256) void k_flash(const __hip_bfloat16* __restrict__ Qb,
    const __hip_bfloat16* __restrict__ Kb, const __hip_bfloat16* __restrict__ Vt,
    const float* __restrict__ amask,
    float* __restrict__ Pstart, float* __restrict__ PbT,
    __hip_bfloat16* __restrict__ Aout) {
  const int q0 = blockIdx.x * 64;
  const int bh = blockIdx.y;                 // PHASE0: h, PHASE1: b*16+h
  const int b  = PHASE ? (bh >> 4) : 0;
  const int h  = PHASE ? (bh & 15) : bh;
  const int tid = threadIdx.x;
  const int w = tid >> 6;
  const int lane = tid & 63;
  const int l15 = lane & 15, g = lane >> 4;

  const int t1 = (q0 >= 128) ? max(128, (q0 - 103) & ~31) : 128;
  const int nt1 = (q0 + 64 > t1) ? (q0 + 64 - t1) / 32 : 0;
  const int ntiles = 4 + nt1;
  const int nfrags = ntiles * 2;             // <= 20

  __shared__ float redm[4][64];
  __shared__ float reds[4][64];
  __shared__ __align__(16) char plds[(PHASE ? 64 * PLDS_STRIDE : 16)];

  const size_t qkbase = (size_t)bh * S_LEN;

  bf16x8 af[4][4];
  #pragma unroll
  for (int mi = 0; mi < 4; mi++)
    #pragma unroll
    for (int dt = 0; dt < 4; dt++)
      af[mi][dt] = *(const bf16x8*)(Qb + (qkbase + q0 + mi*16 + l15)*HDIM + dt*32 + g*8);

  int kb[5];
  #pragma unroll
  for (int fi = 0; fi < 5; fi++) {
    int f = w + fi*4;
    if (f < nfrags) {
      int ti = f >> 1;
      int kt = (ti < 4) ? ti*32 : t1 + (ti-4)*32;
      kb[fi] = kt + (f & 1)*16;
    } else kb[fi] = -1;
  }

  f32x4 sacc[4][5];
  #pragma unroll
  for (int mi = 0; mi < 4; mi++)
    #pragma unroll
    for (int fi = 0; fi < 5; fi++)
      #pragma unroll
      for (int r = 0; r < 4; r++) sacc[mi][fi][r] = 0.f;

  #pragma unroll
  for (int fi = 0; fi < 5; fi++) {
    if (kb[fi] < 0) continue;
    #pragma unroll
    for (int dt = 0; dt < 4; dt++) {
      bf16x8 bfr = *(const bf16x8*)(Kb + (qkbase + kb[fi] + l15)*HDIM + dt*32 + g*8);
      #pragma unroll
      for (int mi = 0; mi < 4; mi++)
        sacc[mi][fi] = __builtin_amdgcn_mfma_f32_16x16x32_bf16(af[mi][dt], bfr, sacc[mi][fi], 0, 0, 0);
    }
  }

  #pragma unroll
  for (int fi = 0; fi < 5; fi++) {
    if (kb[fi] < 0) continue;
    int kcol = kb[fi] + l15;
    float amv = amask[b * S_LEN + kcol];
    #pragma unroll
    for (int mi = 0; mi < 4; mi++)
      #pragma unroll
      for (int r = 0; r < 4; r++) {
        int q = q0 + mi*16 + g*4 + r;
        bool ok = (kcol <= q) && ((kcol < SB) || (kcol + RB >= q));
        sacc[mi][fi][r] = ok ? sacc[mi][fi][r] * 0.08838834764831845f + amv : -3.0e38f;
      }
  }

  float rmax[4][4];
  #pragma unroll
  for (int mi = 0; mi < 4; mi++)
    #pragma unroll
    for (int r = 0; r < 4; r++) {
      float m = -3.4e38f;
      #pragma unroll
      for (int fi = 0; fi < 5; fi++)
        if (kb[fi] >= 0) m = fmaxf(m, sacc[mi][fi][r]);
      #pragma unroll
      for (int d = 1; d < 16; d <<= 1) m = fmaxf(m, __shfl_xor(m, d));
      rmax[mi][r] = m;
    }
  if (l15 == 0)
    #pragma unroll
    for (int mi = 0; mi < 4; mi++)
      #pragma unroll
      for (int r = 0; r < 4; r++) redm[w][mi*16 + g*4 + r] = rmax[mi][r];
  __syncthreads();
  #pragma unroll
  for (int mi = 0; mi < 4; mi++)
    #pragma unroll
    for (int r = 0; r < 4; r++) {
      int q = mi*16 + g*4 + r;
      rmax[mi][r] = fmaxf(fmaxf(redm[0][q], redm[1][q]), fmaxf(redm[2][q], redm[3][q]));
    }

  float rsum[4][4];
  #pragma unroll
  for (int mi = 0; mi < 4; mi++)
    #pragma unroll
    for (int r = 0; r < 4; r++) rsum[mi][r] = 0.f;
  #pragma unroll
  for (int fi = 0; fi < 5; fi++) {
    if (kb[fi] < 0) continue;
    #pragma unroll
    for (int mi = 0; mi < 4; mi++)
      #pragma unroll
      for (int r = 0; r < 4; r++) {
        float e = __expf(sacc[mi][fi][r] - rmax[mi][r]);
        sacc[mi][fi][r] = e;
        rsum[mi][r] += e;
      }
  }
  #pragma unroll
  for (int mi = 0; mi < 4; mi++)
    #pragma unroll
    for (int r = 0; r < 4; r++) {
      float s = rsum[mi][r];
      #pragma unroll
      for (int d = 1; d < 16; d <<= 1) s += __shfl_xor(s, d);
      rsum[mi][r] = s;
    }
  if (l15 == 0)
    #pragma unroll
    for (int mi = 0; mi < 4; mi++)
      #pragma unroll
      for (int r = 0; r < 4; r++) reds[w][mi*16 + g*4 + r] = rsum[mi][r];
  __syncthreads();
  float inv[4][4];
  #pragma unroll
  for (int mi = 0; mi < 4; mi++)
    #pragma unroll
    for (int r = 0; r < 4; r++) {
      int q = mi*16 + g*4 + r;
      inv[mi][r] = 1.0f / (reds[0][q] + reds[1][q] + reds[2][q] + reds[3][q]);
    }

  if constexpr (PHASE == 0) {
    #pragma unroll
    for (int fi = 0; fi < 5; fi++) {
      if (kb[fi] < 0) continue;
      int kcol = kb[fi] + l15;
      #pragma unroll
      for (int mi = 0; mi < 4; mi++)
        #pragma unroll
        for (int r = 0; r < 4; r++) {
          int q = q0 + mi*16 + g*4 + r;
          float p = sacc[mi][fi][r] * inv[mi][r];
          if (kcol < 128)
            Pstart[((size_t)h*128 + kcol)*S_LEN + q] = p;
          if (kcol >= SB && kcol < 1023 && kcol <= q && q - kcol <= RB)
            PbT[((size_t)h*920 + (kcol - SB))*104 + (q - kcol)] = p;
        }
    }
  } else {
    #pragma unroll
    for (int fi = 0; fi < 5; fi++) {
      if (kb[fi] < 0) continue;
      int cc = (w + fi*4)*16 + l15;
      #pragma unroll
      for (int mi = 0; mi < 4; mi++)
        #pragma unroll
        for (int r = 0; r < 4; r++) {
          int qs = mi*16 + g*4 + r;
          *(__hip_bfloat16*)(plds + qs*PLDS_STRIDE + cc*2) =
              __float2bfloat16(sacc[mi][fi][r] * inv[mi][r]);
        }
    }
    __syncthreads();
    f32x4 pacc[4][2];
    #pragma unroll
    for (int mi = 0; mi < 4; mi++)
      #pragma unroll
      for (int nj = 0; nj < 2; nj++)
        #pragma unroll
        for (int r = 0; r < 4; r++) pacc[mi][nj][r] = 0.f;
    for (int ti = 0; ti < ntiles; ti++) {
      int kt = (ti < 4) ? ti*32 : t1 + (ti-4)*32;
      int cb = ti*32;
      bf16x8 pa[4];
      #pragma unroll
      for (int mi = 0; mi < 4; mi++)
        pa[mi] = lds_load8(plds + (mi*16 + l15)*PLDS_STRIDE + (cb + g*8)*2);
      #pragma unroll
      for (int nj = 0; nj < 2; nj++) {
        int d = w*32 + nj*16 + l15;
        bf16x8 vb = *(const bf16x8*)(Vt + ((size_t)bh*HDIM + d)*S_LEN + kt + g*8);
        #pragma unroll
        for (int mi = 0; mi < 4; mi++)
          pacc[mi][nj] = __builtin_amdgcn_mfma_f32_16x16x32_bf16(pa[mi], vb, pacc[mi][nj], 0, 0, 0);
      }
    }
    #pragma unroll
    for (int mi = 0; mi < 4; mi++)
      #pragma unroll
      for (int nj = 0; nj < 2; nj++)
        #pragma unroll
        for (int r = 0; r < 4; r++) {
          int q = q0 + mi*16 + g*4 + r;
          int d = w*32 + nj*16 + l15;
          Aout[((size_t)b*S_LEN + q)*HID + h*HDIM + d] = __float2bfloat16(pacc[mi][nj][r]);
        }
  }
}

// ---------------- stats: wave-per-column prefix scans ----------------
__global__ __launch_bounds__(256) void k_sstart(const float* __restrict__ Pstart,
                                                float* __restrict__ Sstart) {
  int wid = blockIdx.x*4 + (threadIdx.x >> 6);
  int lane = threadIdx.x & 63;
  if (wid >= NHEAD * SB) return;
  int h = wid / SB, k = wid % SB;
  const float* col = Pstart + ((size_t)h*128 + k)*S_LEN;
  float carry = 0.f;
  for (int seg = 0; seg < 16; seg++) {
    int q = seg*64 + lane;
    float v = col[q];
    #pragma unroll
    for (int d = 1; d < 64; d <<= 1) {
      float u = __shfl_up(v, d);
      if (lane >= d) v += u;
    }
    float tot = carry + v;
    int t = q + 1;
    if (t >= TMIN && t < S_LEN)
      Sstart[((size_t)h*SB + k)*NT + (t - TMIN)] = tot;
    carry += __shfl(v, 63);
  }
}

__global__ __launch_bounds__(256) void k_band(const float* __restrict__ PbT,
                                              float* __restrict__ Band) {
  int wid = blockIdx.x*4 + (threadIdx.x >> 6);
  int lane = threadIdx.x & 63;
  if (wid >= NHEAD * 920) return;
  int h = wid / 920, kk = wid % 920;
  int k = kk + SB;
  const float* col = PbT + ((size_t)h*920 + kk)*104;
  float carry = 0.f;
  #pragma unroll
  for (int seg = 0; seg < 2; seg++) {
    int i = seg*64 + lane;
    bool valid = (i <= 102) && (k + i <= 1022);
    float v = valid ? col[i] : 0.f;
    #pragma unroll
    for (int d = 1; d < 64; d <<= 1) {
      float u = __shfl_up(v, d);
      if (lane >= d) v += u;
    }
    float tot = carry + v;
    int t = k + i + 1;
    if (valid && t >= TMIN && t < S_LEN) {
      int j = 102 - i;
      Band[((size_t)h*S_LEN + t)*SB + j] = tot;
    }
    carry += __shfl(v, 63);
  }
}

// ---------------- prob + threefry bernoulli ----------------
__global__ __launch_bounds__(64) void k_mask(const float* __restrict__ Sstart,
    const float* __restrict__ Band, float* __restrict__ Mask) {
  const int t = TMIN + blockIdx.x;
  const int lane = threadIdx.x;
  const int h = lane >> 2, j = lane & 3;
  const float* bb = Band + ((size_t)h*S_LEN + t)*SB;
  float mx = -3.4e38f;
  for (int i = j; i < SB; i += 4)
    mx = fmaxf(mx, Sstart[((size_t)h*SB + i)*NT + (t - TMIN)]);
  for (int i = j; i < RB; i += 4) mx = fmaxf(mx, bb[i]);
  mx = fmaxf(mx, __shfl_xor(mx, 1));
  mx = fmaxf(mx, __shfl_xor(mx, 2));
  if (j == 0) {
    float prob = bb[0] / mx;
    prob = fminf(fmaxf(prob, 0.f), 1.f);
    unsigned a0, a1, b0, b1;
    tf2x32(0u, 42u, 0u, (unsigned)t, a0, a1);
    tf2x32(a0, a1, 0u, (unsigned)h, b0, b1);
    float u = tfu(b0 ^ b1);
    Mask[t*NHEAD + h] = (u < prob) ? 1.f : 0.f;
  }
}

// ---------------- closed-form CAM scan ----------------
__global__ __launch_bounds__(64) void k_scan(const float* __restrict__ Vf,
    const float* __restrict__ Mask, float* __restrict__ Pscan) {
  const int blk = blockIdx.x;       // 0..127
  const int bh = blk >> 1, dc = blk & 1;
  const int h = bh & 15;
  const int lane = threadIdx.x;
  __shared__ float ring[RB * 64];
  __shared__ float marr[NT];
  for (int i = lane; i < NT; i += 64) marr[i] = Mask[(TMIN + i)*NHEAD + h];
  __syncthreads();
  float S = 0.f, P = 0.f;
  const size_t vbase = (size_t)bh * S_LEN * HDIM + dc*64 + lane;
  const size_t pbase = (size_t)bh * HDIM + dc*64 + lane;
  for (int t = TMIN; t < S_LEN; t++) {
    float v0 = Vf[vbase + (size_t)(t - RB) * HDIM];
    float a = fmaf(S, (1.f/103.f), v0);
    float w = marr[t - TMIN] * a;
    P += w;
    Pscan[(size_t)(t - TMIN) * 8192 + pbase] = P;
    int slot = t % RB;
    float old = ring[slot*64 + lane];
    ring[slot*64 + lane] = w;
    S += w;
    if (t >= TMIN + RB) S -= old;
  }
}

__global__ __launch_bounds__(256) void k_vupdate(float* __restrict__ Vf,
    const float* __restrict__ Pscan) {
  size_t idx = (size_t)blockIdx.x * 256 + threadIdx.x;
  int d  = idx & 127;
  int p  = (int)((idx >> 7) & 1023);
  int bh = (int)(idx >> 17);
  if (p < 104) return;
  int hi = min(1023, p + 102);
  int lo = (p <= 206) ? -1 : (p - 1);
  size_t pb = (size_t)bh * HDIM + d;
  float Phi = Pscan[(size_t)(hi - TMIN)*8192 + pb];
  float Plo = (lo < 0) ? 0.f : Pscan[(size_t)(lo - TMIN)*8192 + pb];
  Vf[idx] += (Phi - Plo) * (1.f/103.f);
}

extern "C" void kernel_launch(void* const* d_in, const int* in_sizes, int n_in,
                              void* d_out, int out_size, void* d_ws, size_t ws_size,
                              hipStream_t stream) {
  const float* hs    = (const float*)d_in[0];
  const float* amask = (const float*)d_in[1];
  const int*   pid   = (const int*)d_in[2];
  const float* Wqkv  = (const float*)d_in[3];
  const float* bqkv  = (const float*)d_in[4];
  const float* Wd    = (const float*)d_in[5];
  const float* bd    = (const float*)d_in[6];
  float* Out = (float*)d_out;

  char* ws = (char*)d_ws;
  size_t off = 0;
  auto alloc = [&](size_t bytes) {
    char* p = ws + off;
    off += (bytes + 255) & ~(size_t)255;
    return p;
  };
  __hip_bfloat16* Xb     = (__hip_bfloat16*)alloc(16777216);  // 4096x2048 bf16
  __hip_bfloat16* WqkvT  = (__hip_bfloat16*)alloc(25165824);  // 6144x2048 bf16
  __hip_bfloat16* WdT    = (__hip_bfloat16*)alloc(8388608);   // 2048x2048 bf16
  __hip_bfloat16* Qb     = (__hip_bfloat16*)alloc(16777216);  // (4,16,1024,128) bf16
  __hip_bfloat16* Kb     = (__hip_bfloat16*)alloc(16777216);
  float*          Vf     = (float*)alloc(33554432);           // (4,16,1024,128) f32
  __hip_bfloat16* Vt     = (__hip_bfloat16*)alloc(16777216);  // (64,128,1024) bf16
  float*          Pstart = (float*)alloc(8388608);            // (16,128,1024) f32
  float*          PbT    = (float*)alloc(6123520);            // (16,920,104) f32
  float*          Sstart = (float*)alloc(5392256);            // (16,103,818) f32
  float*          Band   = (float*)alloc(6750208);            // (16,1024,103) f32
  float*          Mask   = (float*)alloc(65536);              // (1024,16) f32
  float*          Pscan  = (float*)alloc(26804224);           // (818,8192) f32
  __hip_bfloat16* Aout   = (__hip_bfloat16*)alloc(16777216);  // 4096x2048 bf16

  k_cast_bf16<<<8192, 256, 0, stream>>>(hs, Xb, 4096 * 2048 / 4);
  k_transpose_cast<<<dim3(192, 64), dim3(32, 8), 0, stream>>>(Wqkv, WqkvT, 2048, 6144);
  k_transpose_cast<<<dim3(64, 64), dim3(32, 8), 0, stream>>>(Wd, WdT, 2048, 2048);
  k_gemm_qkv3<<<dim3(32, 16), 512, 0, stream>>>(Xb, WqkvT, bqkv, pid, Qb, Kb, Vf);
  k_flash<0><<<dim3(16, 16), 256, 0, stream>>>(Qb, Kb, nullptr, amask, Pstart, PbT, nullptr);
  k_sstart<<<412, 256, 0, stream>>>(Pstart, Sstart);
  k_band<<<3680, 256, 0, stream>>>(PbT, Band);
  k_mask<<<818, 64, 0, stream>>>(Sstart, Band, Mask);
  k_scan<<<128, 64, 0, stream>>>(Vf, Mask, Pscan);
  k_vupdate<<<32768, 256, 0, stream>>>(Vf, Pscan);
  k_vtrans<<<dim3(32, 4, 64), dim3(32, 8), 0, stream>>>(Vf, Vt);
  k_flash<1><<<dim3(16, 64), 256, 0, stream>>>(Qb, Kb, Vt, amask, nullptr, nullptr, Aout);
  k_gemm_out3<<<dim3(32, 8), 512, 0, stream>>>(Aout, WdT, bd, Out);
}

// Round 5
// 454.492 us; speedup vs baseline: 1.2488x; 1.2488x over previous
//
#include <hip/hip_runtime.h>
#include <hip/hip_bf16.h>

// GPTNeoXAttention + CAM mask pipeline, MI355X (gfx950)
// B=4 S=1024 HID=2048 NH=16 HD=128 ROT=32, sb=rb=103
//
// R5: GEMMs reverted to the known-best R2 128x128 core (+XCD swizzle);
// k_scan software-pipelined (chunked prefetch of v0 + ring reads);
// k_vupdate fused into k_vtrans (no Vf write-back).

#define S_LEN 1024
#define NHEAD 16
#define HDIM  128
#define HID   2048
#define SB    103
#define RB    103
#define TMIN  206
#define NT    818

typedef __bf16 bf16x8 __attribute__((ext_vector_type(8)));
typedef __bf16 bf16x4 __attribute__((ext_vector_type(4)));
typedef float  f32x4  __attribute__((ext_vector_type(4)));

#define PLDS_STRIDE 648

// ---------------- threefry2x32 (JAX-compatible) ----------------
__device__ __forceinline__ void tf2x32(unsigned k0, unsigned k1,
                                       unsigned x0, unsigned x1,
                                       unsigned& o0, unsigned& o1) {
  unsigned ks2 = k0 ^ k1 ^ 0x1BD11BDAu;
  x0 += k0; x1 += k1;
#define TFR(r) { x0 += x1; x1 = (x1 << r) | (x1 >> (32 - r)); x1 ^= x0; }
  TFR(13) TFR(15) TFR(26) TFR(6)   x0 += k1;  x1 += ks2 + 1u;
  TFR(17) TFR(29) TFR(16) TFR(24)  x0 += ks2; x1 += k0 + 2u;
  TFR(13) TFR(15) TFR(26) TFR(6)   x0 += k0;  x1 += k1 + 3u;
  TFR(17) TFR(29) TFR(16) TFR(24)  x0 += k1;  x1 += ks2 + 4u;
  TFR(13) TFR(15) TFR(26) TFR(6)   x0 += ks2; x1 += k0 + 5u;
#undef TFR
  o0 = x0; o1 = x1;
}
__device__ __forceinline__ float tfu(unsigned b) {
  return __builtin_bit_cast(float, (b >> 9) | 0x3f800000u) - 1.0f;
}

// ---------------- casts / transposes ----------------
__global__ __launch_bounds__(256) void k_cast_bf16(const float* __restrict__ in,
                                                   __hip_bfloat16* __restrict__ out, int n4) {
  int i = blockIdx.x * 256 + threadIdx.x;
  if (i >= n4) return;
  float4 v = ((const float4*)in)[i];
  __hip_bfloat162 lo = __float22bfloat162_rn(make_float2(v.x, v.y));
  __hip_bfloat162 hi = __float22bfloat162_rn(make_float2(v.z, v.w));
  ((__hip_bfloat162*)out)[2*i]   = lo;
  ((__hip_bfloat162*)out)[2*i+1] = hi;
}

// W[K][N] f32 -> Wt[N][K] bf16
__global__ __launch_bounds__(256) void k_transpose_cast(const float* __restrict__ W,
                                                        __hip_bfloat16* __restrict__ Wt,
                                                        int K, int N) {
  __shared__ float tile[32][33];
  int n0 = blockIdx.x * 32, k0 = blockIdx.y * 32;
  int tx = threadIdx.x, ty = threadIdx.y;
  #pragma unroll
  for (int i = 0; i < 32; i += 8)
    tile[ty + i][tx] = W[(size_t)(k0 + ty + i) * N + n0 + tx];
  __syncthreads();
  #pragma unroll
  for (int i = 0; i < 32; i += 8)
    Wt[(size_t)(n0 + ty + i) * K + k0 + tx] = __float2bfloat16(tile[tx][ty + i]);
}

// Vf [bh][k][d] f32 + CAM delta -> Vt [bh][d][k] bf16  (fused vupdate+vtrans)
__global__ __launch_bounds__(256) void k_vtrans_upd(const float* __restrict__ Vf,
                                                    const float* __restrict__ Pscan,
                                                    __hip_bfloat16* __restrict__ Vt) {
  __shared__ float tile[32][33];
  int k0 = blockIdx.x * 32, d0 = blockIdx.y * 32, bh = blockIdx.z;
  int tx = threadIdx.x, ty = threadIdx.y;
  #pragma unroll
  for (int i = 0; i < 32; i += 8) {
    int p = k0 + ty + i;
    int d = d0 + tx;
    float v = Vf[((size_t)bh * S_LEN + p) * HDIM + d];
    if (p >= 104) {
      int hi = min(1023, p + 102);
      int lo = (p <= 206) ? -1 : (p - 1);   // max(206,p)-1; -1 encodes P=0
      size_t pb = (size_t)bh * HDIM + d;
      float Phi = Pscan[(size_t)(hi - TMIN) * 8192 + pb];
      float Plo = (lo < 0) ? 0.f : Pscan[(size_t)(lo - TMIN) * 8192 + pb];
      v += (Phi - Plo) * (1.f / 103.f);
    }
    tile[ty + i][tx] = v;
  }
  __syncthreads();
  #pragma unroll
  for (int i = 0; i < 32; i += 8)
    Vt[((size_t)bh * HDIM + (d0 + ty + i)) * S_LEN + k0 + tx] = __float2bfloat16(tile[tx][ty + i]);
}

// ---------------- 128x128 bf16 MFMA GEMM core (R2, known-best) ----------------
__device__ __forceinline__ void gemm128(const char* __restrict__ A, const char* __restrict__ Bt,
                                        int K, long rowA0, long rowB0, char* lds,
                                        f32x4 (&acc)[4][4]) {
  const int tid  = threadIdx.x;
  const int lane = tid & 63;
  const int wave = tid >> 6;
  const int wm = wave >> 1, wn = wave & 1;
  const int l4  = lane >> 2;
  const int lkb = (lane & 3) * 16;
  const int rlo = lane & 15;
  const int khi = (lane >> 4) * 16;
  const long strA = (long)K * 2;
  for (int k0 = 0; k0 < K; k0 += 32) {
    #pragma unroll
    for (int q = 0; q < 2; q++) {
      long ra = rowA0 + wave*32 + q*16 + l4;
      const char* ga = A + ra*strA + (long)k0*2 + lkb;
      __builtin_amdgcn_global_load_lds((const __attribute__((address_space(1))) void*)ga,
          (__attribute__((address_space(3))) void*)(lds + wave*2048 + q*1024), 16, 0, 0);
      long rbn = rowB0 + wave*32 + q*16 + l4;
      const char* gb = Bt + rbn*strA + (long)k0*2 + lkb;
      __builtin_amdgcn_global_load_lds((const __attribute__((address_space(1))) void*)gb,
          (__attribute__((address_space(3))) void*)(lds + 8192 + wave*2048 + q*1024), 16, 0, 0);
    }
    __syncthreads();
    bf16x8 af[4], bfr[4];
    #pragma unroll
    for (int mf = 0; mf < 4; mf++)
      af[mf] = *(const bf16x8*)(lds + (wm*64 + mf*16 + rlo)*64 + khi);
    #pragma unroll
    for (int nf = 0; nf < 4; nf++)
      bfr[nf] = *(const bf16x8*)(lds + 8192 + (wn*64 + nf*16 + rlo)*64 + khi);
    #pragma unroll
    for (int mf = 0; mf < 4; mf++)
      #pragma unroll
      for (int nf = 0; nf < 4; nf++)
        acc[mf][nf] = __builtin_amdgcn_mfma_f32_16x16x32_bf16(af[mf], bfr[nf], acc[mf][nf], 0, 0, 0);
    __syncthreads();
  }
}

// ---------------- GEMM qkv + bias + RoPE + scatter ----------------
__global__ __launch_bounds__(256) void k_gemm_qkv(const __hip_bfloat16* __restrict__ Xb,
    const __hip_bfloat16* __restrict__ WqkvT, const float* __restrict__ bqkv,
    const int* __restrict__ pid,
    __hip_bfloat16* __restrict__ Qb, __hip_bfloat16* __restrict__ Kb, float* __restrict__ Vf) {
  __shared__ __align__(16) char lds[16384];
  f32x4 acc[4][4];
  #pragma unroll
  for (int m = 0; m < 4; m++)
    #pragma unroll
    for (int n = 0; n < 4; n++)
      #pragma unroll
      for (int r = 0; r < 4; r++) acc[m][n][r] = 0.f;
  // XCD-bijective swizzle: nwg = 1536 = 8 * 192
  int flat = blockIdx.y * 32 + blockIdx.x;
  int swz = (flat & 7) * 192 + (flat >> 3);
  int bm = swz & 31, bn = swz >> 5;
  gemm128((const char*)Xb, (const char*)WqkvT, HID, (long)bm*128, (long)bn*128, lds, acc);
  const int lane = threadIdx.x & 63, wave = threadIdx.x >> 6;
  const int wm = wave >> 1, wn = wave & 1;
  const int colbase = bn*128 + wn*64;
  const int rowbase = bm*128 + wm*64 + (lane >> 4) * 4;
  // bias
  #pragma unroll
  for (int nf = 0; nf < 4; nf++) {
    int col = colbase + nf*16 + (lane & 15);
    float bias = bqkv[col];
    #pragma unroll
    for (int mf = 0; mf < 4; mf++)
      #pragma unroll
      for (int r = 0; r < 4; r++) acc[mf][nf][r] += bias;
  }
  // RoPE: pair (i, i+16) in frags nf=0,1 at same lane iff colbase%384 in {0,128}
  const int jb = colbase % 384;
  if (jb == 0 || jb == 128) {
    const int i = lane & 15;
    const float invf = exp2f(-(float)i * 0.8304820237218406f); // 10000^(-i/16)
    #pragma unroll
    for (int mf = 0; mf < 4; mf++) {
      #pragma unroll
      for (int r = 0; r < 4; r++) {
        int row = rowbase + mf*16 + r;
        int b = row >> 10, s = row & 1023;
        float th = (float)pid[b * S_LEN + s] * invf;
        float sn, cs;
        sincosf(th, &sn, &cs);
        float x1 = acc[mf][0][r], x2 = acc[mf][1][r];
        acc[mf][0][r] = x1*cs - x2*sn;
        acc[mf][1][r] = x2*cs + x1*sn;
      }
    }
  }
  // scatter
  #pragma unroll
  for (int mf = 0; mf < 4; mf++) {
    #pragma unroll
    for (int nf = 0; nf < 4; nf++) {
      int col = colbase + nf*16 + (lane & 15);
      int h = col / 384, j = col % 384;
      #pragma unroll
      for (int r = 0; r < 4; r++) {
        int row = rowbase + mf*16 + r;
        int b = row >> 10, s = row & 1023;
        size_t base = ((size_t)(b*NHEAD + h)*S_LEN + s)*HDIM;
        float v = acc[mf][nf][r];
        if (j < 128)      Qb[base + j]       = __float2bfloat16(v);
        else if (j < 256) Kb[base + j - 128] = __float2bfloat16(v);
        else              Vf[base + j - 256] = v;
      }
    }
  }
}

// ---------------- GEMM out-proj + bias ----------------
__global__ __launch_bounds__(256) void k_gemm_out(const __hip_bfloat16* __restrict__ Ab,
    const __hip_bfloat16* __restrict__ WdT, const float* __restrict__ bd,
    float* __restrict__ Out) {
  __shared__ __align__(16) char lds[16384];
  f32x4 acc[4][4];
  #pragma unroll
  for (int m = 0; m < 4; m++)
    #pragma unroll
    for (int n = 0; n < 4; n++)
      #pragma unroll
      for (int r = 0; r < 4; r++) acc[m][n][r] = 0.f;
  // XCD-bijective swizzle: nwg = 512 = 8 * 64
  int flat = blockIdx.y * 32 + blockIdx.x;
  int swz = (flat & 7) * 64 + (flat >> 3);
  int bm = swz & 31, bn = swz >> 5;
  gemm128((const char*)Ab, (const char*)WdT, HID, (long)bm*128, (long)bn*128, lds, acc);
  const int lane = threadIdx.x & 63, wave = threadIdx.x >> 6;
  const int wm = wave >> 1, wn = wave & 1;
  const int colbase = bn*128 + wn*64;
  const int rowbase = bm*128 + wm*64 + (lane >> 4) * 4;
  #pragma unroll
  for (int nf = 0; nf < 4; nf++) {
    int col = colbase + nf*16 + (lane & 15);
    float bias = bd[col];
    #pragma unroll
    for (int mf = 0; mf < 4; mf++)
      #pragma unroll
      for (int r = 0; r < 4; r++) {
        int row = rowbase + mf*16 + r;
        Out[(size_t)row * HID + col] = acc[mf][nf][r] + bias;
      }
  }
}

// ---------------- banded flash attention ----------------
__device__ __forceinline__ bf16x8 lds_load8(const char* p) {
  bf16x4 lo = *(const bf16x4*)p;
  bf16x4 hi = *(const bf16x4*)(p + 8);
  bf16x8 v;
  v[0]=lo[0]; v[1]=lo[1]; v[2]=lo[2]; v[3]=lo[3];
  v[4]=hi[0]; v[5]=hi[1]; v[6]=hi[2]; v[7]=hi[3];
  return v;
}

template<int PHASE>
__global__ __launch_bounds__(256) void k_flash(const __hip_bfloat16* __restrict__ Qb,
    const __hip_bfloat16* __restrict__ Kb, const __hip_bfloat16* __restrict__ Vt,
    const float* __restrict__ amask,
    float* __restrict__ Pstart, float* __restrict__ PbT,
    __hip_bfloat16* __restrict__ Aout) {
  const int q0 = blockIdx.x * 64;
  const int bh = blockIdx.y;                 // PHASE0: h, PHASE1: b*16+h
  const int b  = PHASE ? (bh >> 4) : 0;
  const int h  = PHASE ? (bh & 15) : bh;
  const int tid = threadIdx.x;
  const int w = tid >> 6;
  const int lane = tid & 63;
  const int l15 = lane & 15, g = lane >> 4;

  const int t1 = (q0 >= 128) ? max(128, (q0 - 103) & ~31) : 128;
  const int nt1 = (q0 + 64 > t1) ? (q0 + 64 - t1) / 32 : 0;
  const int ntiles = 4 + nt1;
  const int nfrags = ntiles * 2;             // <= 20

  __shared__ float redm[4][64];
  __shared__ float reds[4][64];
  __shared__ __align__(16) char plds[(PHASE ? 64 * PLDS_STRIDE : 16)];

  const size_t qkbase = (size_t)bh * S_LEN;

  bf16x8 af[4][4];
  #pragma unroll
  for (int mi = 0; mi < 4; mi++)
    #pragma unroll
    for (int dt = 0; dt < 4; dt++)
      af[mi][dt] = *(const bf16x8*)(Qb + (qkbase + q0 + mi*16 + l15)*HDIM + dt*32 + g*8);

  int kb[5];
  #pragma unroll
  for (int fi = 0; fi < 5; fi++) {
    int f = w + fi*4;
    if (f < nfrags) {
      int ti = f >> 1;
      int kt = (ti < 4) ? ti*32 : t1 + (ti-4)*32;
      kb[fi] = kt + (f & 1)*16;
    } else kb[fi] = -1;
  }

  f32x4 sacc[4][5];
  #pragma unroll
  for (int mi = 0; mi < 4; mi++)
    #pragma unroll
    for (int fi = 0; fi < 5; fi++)
      #pragma unroll
      for (int r = 0; r < 4; r++) sacc[mi][fi][r] = 0.f;

  #pragma unroll
  for (int fi = 0; fi < 5; fi++) {
    if (kb[fi] < 0) continue;
    #pragma unroll
    for (int dt = 0; dt < 4; dt++) {
      bf16x8 bfr = *(const bf16x8*)(Kb + (qkbase + kb[fi] + l15)*HDIM + dt*32 + g*8);
      #pragma unroll
      for (int mi = 0; mi < 4; mi++)
        sacc[mi][fi] = __builtin_amdgcn_mfma_f32_16x16x32_bf16(af[mi][dt], bfr, sacc[mi][fi], 0, 0, 0);
    }
  }

  #pragma unroll
  for (int fi = 0; fi < 5; fi++) {
    if (kb[fi] < 0) continue;
    int kcol = kb[fi] + l15;
    float amv = amask[b * S_LEN + kcol];
    #pragma unroll
    for (int mi = 0; mi < 4; mi++)
      #pragma unroll
      for (int r = 0; r < 4; r++) {
        int q = q0 + mi*16 + g*4 + r;
        bool ok = (kcol <= q) && ((kcol < SB) || (kcol + RB >= q));
        sacc[mi][fi][r] = ok ? sacc[mi][fi][r] * 0.08838834764831845f + amv : -3.0e38f;
      }
  }

  float rmax[4][4];
  #pragma unroll
  for (int mi = 0; mi < 4; mi++)
    #pragma unroll
    for (int r = 0; r < 4; r++) {
      float m = -3.4e38f;
      #pragma unroll
      for (int fi = 0; fi < 5; fi++)
        if (kb[fi] >= 0) m = fmaxf(m, sacc[mi][fi][r]);
      #pragma unroll
      for (int d = 1; d < 16; d <<= 1) m = fmaxf(m, __shfl_xor(m, d));
      rmax[mi][r] = m;
    }
  if (l15 == 0)
    #pragma unroll
    for (int mi = 0; mi < 4; mi++)
      #pragma unroll
      for (int r = 0; r < 4; r++) redm[w][mi*16 + g*4 + r] = rmax[mi][r];
  __syncthreads();
  #pragma unroll
  for (int mi = 0; mi < 4; mi++)
    #pragma unroll
    for (int r = 0; r < 4; r++) {
      int q = mi*16 + g*4 + r;
      rmax[mi][r] = fmaxf(fmaxf(redm[0][q], redm[1][q]), fmaxf(redm[2][q], redm[3][q]));
    }

  float rsum[4][4];
  #pragma unroll
  for (int mi = 0; mi < 4; mi++)
    #pragma unroll
    for (int r = 0; r < 4; r++) rsum[mi][r] = 0.f;
  #pragma unroll
  for (int fi = 0; fi < 5; fi++) {
    if (kb[fi] < 0) continue;
    #pragma unroll
    for (int mi = 0; mi < 4; mi++)
      #pragma unroll
      for (int r = 0; r < 4; r++) {
        float e = __expf(sacc[mi][fi][r] - rmax[mi][r]);
        sacc[mi][fi][r] = e;
        rsum[mi][r] += e;
      }
  }
  #pragma unroll
  for (int mi = 0; mi < 4; mi++)
    #pragma unroll
    for (int r = 0; r < 4; r++) {
      float s = rsum[mi][r];
      #pragma unroll
      for (int d = 1; d < 16; d <<= 1) s += __shfl_xor(s, d);
      rsum[mi][r] = s;
    }
  if (l15 == 0)
    #pragma unroll
    for (int mi = 0; mi < 4; mi++)
      #pragma unroll
      for (int r = 0; r < 4; r++) reds[w][mi*16 + g*4 + r] = rsum[mi][r];
  __syncthreads();
  float inv[4][4];
  #pragma unroll
  for (int mi = 0; mi < 4; mi++)
    #pragma unroll
    for (int r = 0; r < 4; r++) {
      int q = mi*16 + g*4 + r;
      inv[mi][r] = 1.0f / (reds[0][q] + reds[1][q] + reds[2][q] + reds[3][q]);
    }

  if constexpr (PHASE == 0) {
    #pragma unroll
    for (int fi = 0; fi < 5; fi++) {
      if (kb[fi] < 0) continue;
      int kcol = kb[fi] + l15;
      #pragma unroll
      for (int mi = 0; mi < 4; mi++)
        #pragma unroll
        for (int r = 0; r < 4; r++) {
          int q = q0 + mi*16 + g*4 + r;
          float p = sacc[mi][fi][r] * inv[mi][r];
          if (kcol < 128)
            Pstart[((size_t)h*128 + kcol)*S_LEN + q] = p;
          if (kcol >= SB && kcol < 1023 && kcol <= q && q - kcol <= RB)
            PbT[((size_t)h*920 + (kcol - SB))*104 + (q - kcol)] = p;
        }
    }
  } else {
    #pragma unroll
    for (int fi = 0; fi < 5; fi++) {
      if (kb[fi] < 0) continue;
      int cc = (w + fi*4)*16 + l15;
      #pragma unroll
      for (int mi = 0; mi < 4; mi++)
        #pragma unroll
        for (int r = 0; r < 4; r++) {
          int qs = mi*16 + g*4 + r;
          *(__hip_bfloat16*)(plds + qs*PLDS_STRIDE + cc*2) =
              __float2bfloat16(sacc[mi][fi][r] * inv[mi][r]);
        }
    }
    __syncthreads();
    f32x4 pacc[4][2];
    #pragma unroll
    for (int mi = 0; mi < 4; mi++)
      #pragma unroll
      for (int nj = 0; nj < 2; nj++)
        #pragma unroll
        for (int r = 0; r < 4; r++) pacc[mi][nj][r] = 0.f;
    for (int ti = 0; ti < ntiles; ti++) {
      int kt = (ti < 4) ? ti*32 : t1 + (ti-4)*32;
      int cb = ti*32;
      bf16x8 pa[4];
      #pragma unroll
      for (int mi = 0; mi < 4; mi++)
        pa[mi] = lds_load8(plds + (mi*16 + l15)*PLDS_STRIDE + (cb + g*8)*2);
      #pragma unroll
      for (int nj = 0; nj < 2; nj++) {
        int d = w*32 + nj*16 + l15;
        bf16x8 vb = *(const bf16x8*)(Vt + ((size_t)bh*HDIM + d)*S_LEN + kt + g*8);
        #pragma unroll
        for (int mi = 0; mi < 4; mi++)
          pacc[mi][nj] = __builtin_amdgcn_mfma_f32_16x16x32_bf16(pa[mi], vb, pacc[mi][nj], 0, 0, 0);
      }
    }
    #pragma unroll
    for (int mi = 0; mi < 4; mi++)
      #pragma unroll
      for (int nj = 0; nj < 2; nj++)
        #pragma unroll
        for (int r = 0; r < 4; r++) {
          int q = q0 + mi*16 + g*4 + r;
          int d = w*32 + nj*16 + l15;
          Aout[((size_t)b*S_LEN + q)*HID + h*HDIM + d] = __float2bfloat16(pacc[mi][nj][r]);
        }
  }
}

// ---------------- stats: wave-per-column prefix scans ----------------
__global__ __launch_bounds__(256) void k_sstart(const float* __restrict__ Pstart,
                                                float* __restrict__ Sstart) {
  int wid = blockIdx.x*4 + (threadIdx.x >> 6);
  int lane = threadIdx.x & 63;
  if (wid >= NHEAD * SB) return;
  int h = wid / SB, k = wid % SB;
  const float* col = Pstart + ((size_t)h*128 + k)*S_LEN;
  float carry = 0.f;
  for (int seg = 0; seg < 16; seg++) {
    int q = seg*64 + lane;
    float v = col[q];
    #pragma unroll
    for (int d = 1; d < 64; d <<= 1) {
      float u = __shfl_up(v, d);
      if (lane >= d) v += u;
    }
    float tot = carry + v;
    int t = q + 1;
    if (t >= TMIN && t < S_LEN)
      Sstart[((size_t)h*SB + k)*NT + (t - TMIN)] = tot;
    carry += __shfl(v, 63);
  }
}

__global__ __launch_bounds__(256) void k_band(const float* __restrict__ PbT,
                                              float* __restrict__ Band) {
  int wid = blockIdx.x*4 + (threadIdx.x >> 6);
  int lane = threadIdx.x & 63;
  if (wid >= NHEAD * 920) return;
  int h = wid / 920, kk = wid % 920;
  int k = kk + SB;
  const float* col = PbT + ((size_t)h*920 + kk)*104;
  float carry = 0.f;
  #pragma unroll
  for (int seg = 0; seg < 2; seg++) {
    int i = seg*64 + lane;
    bool valid = (i <= 102) && (k + i <= 1022);
    float v = valid ? col[i] : 0.f;
    #pragma unroll
    for (int d = 1; d < 64; d <<= 1) {
      float u = __shfl_up(v, d);
      if (lane >= d) v += u;
    }
    float tot = carry + v;
    int t = k + i + 1;
    if (valid && t >= TMIN && t < S_LEN) {
      int j = 102 - i;
      Band[((size_t)h*S_LEN + t)*SB + j] = tot;
    }
    carry += __shfl(v, 63);
  }
}

// ---------------- prob + threefry bernoulli ----------------
__global__ __launch_bounds__(64) void k_mask(const float* __restrict__ Sstart,
    const float* __restrict__ Band, float* __restrict__ Mask) {
  const int t = TMIN + blockIdx.x;
  const int lane = threadIdx.x;
  const int h = lane >> 2, j = lane & 3;
  const float* bb = Band + ((size_t)h*S_LEN + t)*SB;
  float mx = -3.4e38f;
  for (int i = j; i < SB; i += 4)
    mx = fmaxf(mx, Sstart[((size_t)h*SB + i)*NT + (t - TMIN)]);
  for (int i = j; i < RB; i += 4) mx = fmaxf(mx, bb[i]);
  mx = fmaxf(mx, __shfl_xor(mx, 1));
  mx = fmaxf(mx, __shfl_xor(mx, 2));
  if (j == 0) {
    float prob = bb[0] / mx;
    prob = fminf(fmaxf(prob, 0.f), 1.f);
    unsigned a0, a1, b0, b1;
    tf2x32(0u, 42u, 0u, (unsigned)t, a0, a1);
    tf2x32(a0, a1, 0u, (unsigned)h, b0, b1);
    float u = tfu(b0 ^ b1);
    Mask[t*NHEAD + h] = (u < prob) ? 1.f : 0.f;
  }
}

// ---------------- closed-form CAM scan (software-pipelined) ----------------
__global__ __launch_bounds__(64) void k_scan(const float* __restrict__ Vf,
    const float* __restrict__ Mask, float* __restrict__ Pscan) {
  const int blk = blockIdx.x;       // 0..127
  const int bh = blk >> 1, dc = blk & 1;
  const int h = bh & 15;
  const int lane = threadIdx.x;
  __shared__ float ring[RB * 64];
  __shared__ float marr[NT];
  for (int i = lane; i < NT; i += 64) marr[i] = Mask[(TMIN + i)*NHEAD + h];
  __syncthreads();
  float S = 0.f, P = 0.f;
  const size_t vbase = (size_t)bh * S_LEN * HDIM + dc*64 + lane;
  const size_t pbase = (size_t)bh * HDIM + dc*64 + lane;
  float cur[8], nxt[8];
  #pragma unroll
  for (int u = 0; u < 8; u++)
    cur[u] = Vf[vbase + (size_t)(TMIN - RB + u) * HDIM];
  for (int t0 = TMIN; t0 < S_LEN; t0 += 8) {
    // prefetch next chunk's v0
    #pragma unroll
    for (int u = 0; u < 8; u++) {
      int t = t0 + 8 + u;
      if (t < S_LEN) nxt[u] = Vf[vbase + (size_t)(t - RB) * HDIM];
    }
    // prefetch this chunk's ring entries (slots distinct; written 103 steps ago)
    float olds[8];
    #pragma unroll
    for (int u = 0; u < 8; u++) {
      int t = t0 + u;
      olds[u] = (t < S_LEN && t >= TMIN + RB) ? ring[(t % RB)*64 + lane] : 0.f;
    }
    // serial updates (VALU only)
    #pragma unroll
    for (int u = 0; u < 8; u++) {
      int t = t0 + u;
      if (t < S_LEN) {
        float a = fmaf(S, (1.f/103.f), cur[u]);
        float w = marr[t - TMIN] * a;
        P += w;
        Pscan[(size_t)(t - TMIN) * 8192 + pbase] = P;
        ring[(t % RB)*64 + lane] = w;
        S += w - olds[u];
        cur[u] = nxt[u];
      }
    }
  }
}

extern "C" void kernel_launch(void* const* d_in, const int* in_sizes, int n_in,
                              void* d_out, int out_size, void* d_ws, size_t ws_size,
                              hipStream_t stream) {
  const float* hs    = (const float*)d_in[0];
  const float* amask = (const float*)d_in[1];
  const int*   pid   = (const int*)d_in[2];
  const float* Wqkv  = (const float*)d_in[3];
  const float* bqkv  = (const float*)d_in[4];
  const float* Wd    = (const float*)d_in[5];
  const float* bd    = (const float*)d_in[6];
  float* Out = (float*)d_out;

  char* ws = (char*)d_ws;
  size_t off = 0;
  auto alloc = [&](size_t bytes) {
    char* p = ws + off;
    off += (bytes + 255) & ~(size_t)255;
    return p;
  };
  __hip_bfloat16* Xb     = (__hip_bfloat16*)alloc(16777216);  // 4096x2048 bf16
  __hip_bfloat16* WqkvT  = (__hip_bfloat16*)alloc(25165824);  // 6144x2048 bf16
  __hip_bfloat16* WdT    = (__hip_bfloat16*)alloc(8388608);   // 2048x2048 bf16
  __hip_bfloat16* Qb     = (__hip_bfloat16*)alloc(16777216);  // (4,16,1024,128) bf16
  __hip_bfloat16* Kb     = (__hip_bfloat16*)alloc(16777216);
  float*          Vf     = (float*)alloc(33554432);           // (4,16,1024,128) f32
  __hip_bfloat16* Vt     = (__hip_bfloat16*)alloc(16777216);  // (64,128,1024) bf16
  float*          Pstart = (float*)alloc(8388608);            // (16,128,1024) f32
  float*          PbT    = (float*)alloc(6123520);            // (16,920,104) f32
  float*          Sstart = (float*)alloc(5392256);            // (16,103,818) f32
  float*          Band   = (float*)alloc(6750208);            // (16,1024,103) f32
  float*          Mask   = (float*)alloc(65536);              // (1024,16) f32
  float*          Pscan  = (float*)alloc(26804224);           // (818,8192) f32
  __hip_bfloat16* Aout   = (__hip_bfloat16*)alloc(16777216);  // 4096x2048 bf16

  k_cast_bf16<<<8192, 256, 0, stream>>>(hs, Xb, 4096 * 2048 / 4);
  k_transpose_cast<<<dim3(192, 64), dim3(32, 8), 0, stream>>>(Wqkv, WqkvT, 2048, 6144);
  k_transpose_cast<<<dim3(64, 64), dim3(32, 8), 0, stream>>>(Wd, WdT, 2048, 2048);
  k_gemm_qkv<<<dim3(32, 48), 256, 0, stream>>>(Xb, WqkvT, bqkv, pid, Qb, Kb, Vf);
  k_flash<0><<<dim3(16, 16), 256, 0, stream>>>(Qb, Kb, nullptr, amask, Pstart, PbT, nullptr);
  k_sstart<<<412, 256, 0, stream>>>(Pstart, Sstart);
  k_band<<<3680, 256, 0, stream>>>(PbT, Band);
  k_mask<<<818, 64, 0, stream>>>(Sstart, Band, Mask);
  k_scan<<<128, 64, 0, stream>>>(Vf, Mask, Pscan);
  k_vtrans_upd<<<dim3(32, 4, 64), dim3(32, 8), 0, stream>>>(Vf, Pscan, Vt);
  k_flash<1><<<dim3(16, 64), 256, 0, stream>>>(Qb, Kb, Vt, amask, nullptr, nullptr, Aout);
  k_gemm_out<<<dim3(32, 16), 256, 0, stream>>>(Aout, WdT, bd, Out);
}